// Round 8
// baseline (252.951 us; speedup 1.0000x reference)
//
#include <hip/hip_runtime.h>
#include <stdint.h>

#define NB 8192
#define DD 256

typedef unsigned short ushort_t;
typedef __attribute__((ext_vector_type(8))) short bf16x8;
typedef __attribute__((ext_vector_type(4))) float f32x4;

// ==================== workspace layout (9306112 B <= proven 10092544) ====================
#define OFF_DIAG   0          // f32[8192]
#define OFF_NEG    32768      // int[8192]
#define OFF_FBROWS 65536      // int[64] (1KB region)
#define OFF_ACC    66560      // f32 acc @+0, int fbcount @+4, u64 fbbest[64] @+8 (520B; 1KB region)
#define OFF_BANDP  131072     // int[16][8192] partials (512 KB)
#define OFF_W1T    655360     // bf16[256][512]  (256 KB, swizzled)
#define OFF_TB     917504     // bf16[8192][256] (4 MB, swizzled)
#define OFF_VB     5111808    // bf16[8192][256] (4 MB, swizzled) -> end 9306112

__device__ __forceinline__ unsigned short f2bf(float x) {
    uint32_t u = __float_as_uint(x);
    return (unsigned short)((u + 0x7FFFu + ((u >> 16) & 1u)) >> 16);
}

__device__ __forceinline__ uint4 packbf8(float4 x, float4 y) {
    uint4 o;
    o.x = (uint32_t)f2bf(x.x) | ((uint32_t)f2bf(x.y) << 16);
    o.y = (uint32_t)f2bf(x.z) | ((uint32_t)f2bf(x.w) << 16);
    o.z = (uint32_t)f2bf(y.x) | ((uint32_t)f2bf(y.y) << 16);
    o.w = (uint32_t)f2bf(y.z) | ((uint32_t)f2bf(y.w) << 16);
    return o;
}

__device__ __forceinline__ unsigned fkey(float s) {
    unsigned u = __float_as_uint(s);
    return (u & 0x80000000u) ? ~u : (u | 0x80000000u);
}

// ---------------- prep_uni: cvt (swizzled), diag, scalar zero-init ----------------
__global__ __launch_bounds__(256) void prep_uni_kernel(const float* __restrict__ t,
                                                       const float* __restrict__ v,
                                                       ushort_t* __restrict__ tb,
                                                       ushort_t* __restrict__ vb,
                                                       float* __restrict__ diag,
                                                       uint32_t* __restrict__ zeroRegion) {
    const int b = blockIdx.x;
    if (b < 2048) {
        const float* in = (b < 1024) ? t : v;
        ushort_t* out = (b < 1024) ? tb : vb;
        int i = (b & 1023) * 256 + threadIdx.x;     // 16B-chunk id
        int row = i >> 5, cw = i & 31, kb = cw >> 3, c = cw & 7;
        int csrc = c ^ (row & 7);
        const float4* src = (const float4*)(in + (size_t)row * DD + kb * 64 + csrc * 8);
        ((uint4*)out)[i] = packbf8(src[0], src[1]);
    } else {
        if (b == 2048 && threadIdx.x < 130) zeroRegion[threadIdx.x] = 0;  // acc+fbcount+fbbest
        int row = (b - 2048) * 4 + (threadIdx.x >> 6);
        int lane = threadIdx.x & 63;
        float4 a = *(const float4*)(t + (size_t)row * DD + lane * 4);
        float4 bb = *(const float4*)(v + (size_t)row * DD + lane * 4);
        float s = a.x * bb.x + a.y * bb.y + a.z * bb.z + a.w * bb.w;
        #pragma unroll
        for (int off = 32; off; off >>= 1) s += __shfl_down(s, off);
        if (lane == 0) diag[row] = s;
    }
}

// ---------------- mine4: A panel in regs, B LDS-dbuf, 128x512/block, no atomics ----------------
__device__ __forceinline__ void stage_b(const ushort_t* __restrict__ VB, ushort_t* Bs,
                                        int colBase, int kc, int tid) {
    #pragma unroll
    for (int i = 0; i < 4; ++i) {
        int idx = i * 256 + tid;              // 0..1023
        int r = idx >> 3, c8 = idx & 7;       // source pre-swizzled -> linear copy
        __builtin_amdgcn_global_load_lds(
            (const __attribute__((address_space(1))) uint32_t*)(VB + (size_t)(colBase + r) * DD + kc + c8 * 8),
            (__attribute__((address_space(3))) uint32_t*)(Bs + idx * 8), 16, 0, 0);
    }
}

__global__ __launch_bounds__(256, 3) void mine4_kernel(const ushort_t* __restrict__ TB,
                                                       const ushort_t* __restrict__ VB,
                                                       const float* __restrict__ diag,
                                                       int* __restrict__ bandPart) {
    __shared__ ushort_t Bs[2][128 * 64];       // 32 KB
    __shared__ float diag_s[128];

    const int tid = threadIdx.x;
    const int rowBase = blockIdx.x * 128;
    const int chunk = blockIdx.y;              // 512 cols each
    const int lane = tid & 63;
    const int wave = tid >> 6;
    const int wr = wave >> 1, wc = wave & 1;   // 2x2 waves, 64x64 each
    const int lo = lane & 15, hi = lane >> 4;
    const int lx = lo & 7;

    // issue first B stage immediately (overlaps A-loads)
    stage_b(VB, Bs[0], chunk * 512, 0, tid);
    if (tid < 128) diag_s[tid] = diag[rowBase + tid];

    // whole A panel -> registers (32 x bf16x8 = 64 VGPR), one read each
    const ushort_t* Abase = TB + (size_t)(rowBase + wr * 64 + lo) * DD;
    bf16x8 areg[4][4][2];                      // [m][kt][ksl]
    #pragma unroll
    for (int m = 0; m < 4; m++)
        #pragma unroll
        for (int kt = 0; kt < 4; kt++)
            #pragma unroll
            for (int ksl = 0; ksl < 2; ksl++)
                areg[m][kt][ksl] = *(const bf16x8*)(Abase + (size_t)m * 16 * DD + kt * 64 +
                                                    ((((ksl << 2) | hi) ^ lx) << 3));
    __syncthreads();                            // drains stage_b(0) + diag_s visible

    float c0r[4][4];
    #pragma unroll
    for (int m = 0; m < 4; m++)
        #pragma unroll
        for (int q = 0; q < 4; q++)
            c0r[m][q] = diag_s[wr * 64 + m * 16 + hi * 4 + q] - 0.35f;

    int bminR[4][4];
    #pragma unroll
    for (int m = 0; m < 4; m++)
        #pragma unroll
        for (int q = 0; q < 4; q++) bminR[m][q] = 0x7FFFFFFF;

    int step = 0;
    for (int ct = 0; ct < 4; ++ct) {
        f32x4 acc[4][4];
        #pragma unroll
        for (int m = 0; m < 4; m++)
            #pragma unroll
            for (int n = 0; n < 4; n++) acc[m][n] = (f32x4){0.f, 0.f, 0.f, 0.f};

        for (int kt = 0; kt < 4; ++kt) {
            const int buf = step & 1;
            if (step < 15) {
                const int ns = step + 1;
                stage_b(VB, Bs[buf ^ 1], chunk * 512 + (ns >> 2) * 128, (ns & 3) * 64, tid);
            }
            #pragma unroll
            for (int ksl = 0; ksl < 2; ksl++) {
                const int ch = ((((ksl << 2) | hi) ^ lx) << 3);
                bf16x8 b[4];
                #pragma unroll
                for (int n = 0; n < 4; n++)
                    b[n] = *(const bf16x8*)&Bs[buf][(wc * 64 + n * 16 + lo) * 64 + ch];
                #pragma unroll
                for (int m = 0; m < 4; m++)
                    #pragma unroll
                    for (int n = 0; n < 4; n++)
                        acc[m][n] = __builtin_amdgcn_mfma_f32_16x16x32_bf16(areg[m][kt][ksl], b[n], acc[m][n], 0, 0, 0);
            }
            __syncthreads();
            ++step;
        }

        // fold band-min for this col-tile (registers only)
        const int colBase = chunk * 512 + ct * 128;
        #pragma unroll
        for (int m = 0; m < 4; m++)
            #pragma unroll
            for (int q = 0; q < 4; q++) {
                const float c0 = c0r[m][q];
                #pragma unroll
                for (int n = 0; n < 4; n++) {
                    const float tt = acc[m][n][q] - c0;
                    const int gcol = colBase + wc * 64 + n * 16 + lo;
                    int cand = (fabsf(tt) < 0.15f) ? gcol : 0x7FFFFFFF;
                    bminR[m][q] = min(bminR[m][q], cand);
                }
            }
    }

    // plain store of per-chunk partials (block exclusively owns rows x chunk)
    #pragma unroll
    for (int m = 0; m < 4; m++)
        #pragma unroll
        for (int q = 0; q < 4; q++) {
            int bm = bminR[m][q];
            #pragma unroll
            for (int off = 1; off < 16; off <<= 1) bm = min(bm, __shfl_xor(bm, off));
            if (lo == 0)
                bandPart[chunk * NB + rowBase + wr * 64 + m * 16 + hi * 4 + q] = bm;
        }
}

// ---------------- combine: min over 16 partials; collect fallback rows (cap 64) ----------------
__global__ __launch_bounds__(256) void combine4_kernel(const int* __restrict__ bandPart,
                                                       int* __restrict__ neg,
                                                       int* __restrict__ fbrows,
                                                       int* __restrict__ fbcount) {
    int row = blockIdx.x * 256 + threadIdx.x;
    int bmin = 0x7FFFFFFF;
    #pragma unroll
    for (int g = 0; g < 16; g++) bmin = min(bmin, bandPart[g * NB + row]);
    if (bmin < NB) {
        neg[row] = bmin;
    } else {
        neg[row] = (row + 4096) & (NB - 1);     // valid placeholder (patched in prep_head)
        int i = atomicAdd(fbcount, 1);
        if (i < 64) fbrows[i] = row;
    }
}

// ---------------- fixup3: parallel off-diag argmax for empty-band rows ----------------
__global__ __launch_bounds__(256) void fixup3_kernel(const float* __restrict__ tuni,
                                                     const float* __restrict__ vuni,
                                                     const int* __restrict__ fbrows,
                                                     const int* __restrict__ fbcount,
                                                     unsigned long long* __restrict__ fbbest) {
    const int slot = blockIdx.y;
    const int count = min(fbcount[0], 64);
    if (slot >= count) return;
    const int row = fbrows[slot];
    const int tid = threadIdx.x;

    __shared__ float tL[DD];
    tL[tid] = tuni[(size_t)row * DD + tid];
    __syncthreads();

    const int col = blockIdx.x * 256 + tid;
    const float4* vr = (const float4*)(vuni + (size_t)col * DD);
    float d = 0.f;
    #pragma unroll 8
    for (int k4 = 0; k4 < 64; k4++) {
        float4 v = vr[k4];
        const float* tk = &tL[k4 * 4];
        d += v.x * tk[0] + v.y * tk[1] + v.z * tk[2] + v.w * tk[3];
    }
    if (col != row) {
        unsigned long long p = ((unsigned long long)fkey(d) << 32) | (unsigned)(NB - 1 - col);
        atomicMax(&fbbest[slot], p);
    }
}

// ---------------- prep_head: cvt tcross/vcross, W1T (swizzled), + fixup writeback ----------------
__global__ __launch_bounds__(256) void prep_head_kernel(const float* __restrict__ tcross,
                                                        const float* __restrict__ vcross,
                                                        const float* __restrict__ W1,
                                                        ushort_t* __restrict__ tb,
                                                        ushort_t* __restrict__ vb,
                                                        ushort_t* __restrict__ W1T,
                                                        const int* __restrict__ fbrows,
                                                        const int* __restrict__ fbcount,
                                                        const unsigned long long* __restrict__ fbbest,
                                                        int* __restrict__ neg) {
    const int b = blockIdx.x;
    const int tid = threadIdx.x;
    if (b < 2048) {
        const float* in = (b < 1024) ? tcross : vcross;
        ushort_t* out = (b < 1024) ? tb : vb;
        int i = (b & 1023) * 256 + tid;
        int row = i >> 5, cw = i & 31, kb = cw >> 3, c = cw & 7;
        int csrc = c ^ (row & 7);
        const float4* src = (const float4*)(in + (size_t)row * DD + kb * 64 + csrc * 8);
        ((uint4*)out)[i] = packbf8(src[0], src[1]);
    } else if (b < 2080) {
        // W1T[n][k] = bf16(W1[k][n]), chunk-swizzled by n&7 within each 64-k block
        __shared__ float Ls[64][68];
        int tt = b - 2048;
        int kb = tt >> 2, nb = tt & 3;
        int r = tid >> 2, q4 = tid & 3;
        #pragma unroll
        for (int j = 0; j < 4; j++) {
            float4 x = *(const float4*)(W1 + (size_t)(kb * 64 + r) * DD + nb * 64 + q4 * 16 + j * 4);
            *(float4*)&Ls[r][q4 * 16 + j * 4] = x;
        }
        __syncthreads();
        int rn = tid >> 2, cq = (tid & 3) * 2;
        #pragma unroll
        for (int cc = 0; cc < 2; cc++) {
            int c = cq + cc;
            int csrc = c ^ (rn & 7);
            float4 x, y;
            x.x = Ls[csrc * 8 + 0][rn]; x.y = Ls[csrc * 8 + 1][rn];
            x.z = Ls[csrc * 8 + 2][rn]; x.w = Ls[csrc * 8 + 3][rn];
            y.x = Ls[csrc * 8 + 4][rn]; y.y = Ls[csrc * 8 + 5][rn];
            y.z = Ls[csrc * 8 + 6][rn]; y.w = Ls[csrc * 8 + 7][rn];
            *(uint4*)&W1T[(size_t)(nb * 64 + rn) * 512 + kb * 64 + c * 8] = packbf8(x, y);
        }
    } else {
        if (tid < min(fbcount[0], 64))
            neg[fbrows[tid]] = NB - 1 - (int)(unsigned)(fbbest[tid] & 0xFFFFFFFFull);
    }
}

// ==================== MFMA ITM head: 32 rows/block, grid (256,2) ====================
__device__ __forceinline__ void stage_head(const ushort_t* __restrict__ TCB,
                                           const ushort_t* __restrict__ VCB,
                                           const int* __restrict__ neg, int isNeg,
                                           const ushort_t* __restrict__ W1T,
                                           ushort_t* As, ushort_t* Bs,
                                           int rowBase, int kc, int tid) {
    {                                             // A: 32 rows x 64 k (256 loads)
        int r = tid >> 3, c8 = tid & 7;
        const ushort_t* src;
        if (kc < 256) {
            src = TCB + (size_t)(rowBase + r) * DD + kc + c8 * 8;
        } else {
            int rr = isNeg ? neg[rowBase + r] : (rowBase + r);
            int cs = c8 ^ ((r ^ rr) & 7);          // re-key rr&7 -> r&7
            src = VCB + (size_t)rr * DD + (kc - 256) + cs * 8;
        }
        __builtin_amdgcn_global_load_lds(
            (const __attribute__((address_space(1))) uint32_t*)src,
            (__attribute__((address_space(3))) uint32_t*)(As + tid * 8), 16, 0, 0);
    }
    #pragma unroll
    for (int i = 0; i < 8; ++i) {                 // B: 256 cols x 64 k (W1T pre-swizzled)
        int idx = i * 256 + tid;
        int n = idx >> 3, c8 = idx & 7;
        __builtin_amdgcn_global_load_lds(
            (const __attribute__((address_space(1))) uint32_t*)(W1T + (size_t)n * 512 + kc + c8 * 8),
            (__attribute__((address_space(3))) uint32_t*)(Bs + idx * 8), 16, 0, 0);
    }
}

__global__ __launch_bounds__(256) void head3_kernel(const ushort_t* __restrict__ TCB,
                                                    const ushort_t* __restrict__ VCB,
                                                    const ushort_t* __restrict__ W1T,
                                                    const int* __restrict__ neg,
                                                    const float* __restrict__ tcf,
                                                    const float* __restrict__ vcf,
                                                    const float* __restrict__ W1,
                                                    const float* __restrict__ b1,
                                                    const float* __restrict__ W2,
                                                    const float* __restrict__ b2,
                                                    float* __restrict__ acc_out) {
    __shared__ ushort_t As[2][32 * 64];           // 4 KB x2
    __shared__ ushort_t Bs[2][256 * 64];          // 32 KB x2
    __shared__ float dot_l[32];
    __shared__ float logit_l[32];

    const int tid = threadIdx.x;
    const int rowBase = blockIdx.x * 32;
    const int isNeg = blockIdx.y;
    const int lane = tid & 63;
    const int wcv = tid >> 6;                     // wave = col group (4 x 64 cols)
    const int lo = lane & 15, hi = lane >> 4;
    const int lx = lo & 7;

    stage_head(TCB, VCB, neg, isNeg, W1T, As[0], Bs[0], rowBase, 0, tid);

    // inline dot feature (fp32 exact): 8 threads per row
    {
        int r = tid >> 3, e = tid & 7;
        int grow = rowBase + r;
        int vrow = isNeg ? neg[grow] : grow;
        const float4* tp = (const float4*)(tcf + (size_t)grow * DD + e * 32);
        const float4* vp = (const float4*)(vcf + (size_t)vrow * DD + e * 32);
        float sd = 0.f;
        #pragma unroll
        for (int j = 0; j < 8; j++) {
            float4 a = tp[j], v = vp[j];
            sd += a.x * v.x + a.y * v.y + a.z * v.z + a.w * v.w;
        }
        sd += __shfl_xor(sd, 1);
        sd += __shfl_xor(sd, 2);
        sd += __shfl_xor(sd, 4);
        if (e == 0) dot_l[r] = sd;
        if (tid < 32) logit_l[tid] = 0.f;
    }

    f32x4 acc[2][4];
    #pragma unroll
    for (int m = 0; m < 2; m++)
        #pragma unroll
        for (int n = 0; n < 4; n++) acc[m][n] = (f32x4){0.f, 0.f, 0.f, 0.f};

    __syncthreads();

    for (int kt = 0; kt < 8; ++kt) {
        const int buf = kt & 1;
        if (kt < 7)
            stage_head(TCB, VCB, neg, isNeg, W1T, As[buf ^ 1], Bs[buf ^ 1], rowBase, (kt + 1) * 64, tid);
        #pragma unroll
        for (int ksl = 0; ksl < 2; ksl++) {
            const int ch = ((((ksl << 2) | hi) ^ lx) << 3);
            bf16x8 a[2], b[4];
            #pragma unroll
            for (int m = 0; m < 2; m++)
                a[m] = *(const bf16x8*)&As[buf][(m * 16 + lo) * 64 + ch];
            #pragma unroll
            for (int n = 0; n < 4; n++)
                b[n] = *(const bf16x8*)&Bs[buf][(wcv * 64 + n * 16 + lo) * 64 + ch];
            #pragma unroll
            for (int m = 0; m < 2; m++)
                #pragma unroll
                for (int n = 0; n < 4; n++)
                    acc[m][n] = __builtin_amdgcn_mfma_f32_16x16x32_bf16(a[m], b[n], acc[m][n], 0, 0, 0);
        }
        __syncthreads();
    }

    float b1v[4], w5v[4], w2v[4];
    #pragma unroll
    for (int n = 0; n < 4; n++) {
        int cl = wcv * 64 + n * 16 + lo;
        b1v[n] = b1[cl];
        w5v[n] = W1[(size_t)512 * DD + cl];
        w2v[n] = W2[cl];
    }
    #pragma unroll
    for (int m = 0; m < 2; m++) {
        #pragma unroll
        for (int q = 0; q < 4; q++) {
            const int rl = m * 16 + hi * 4 + q;
            const float dt = dot_l[rl];
            float x = 0.f;
            #pragma unroll
            for (int n = 0; n < 4; n++) {
                float h = acc[m][n][q] + b1v[n] + dt * w5v[n];
                x += fmaxf(h, 0.f) * w2v[n];
            }
            #pragma unroll
            for (int off = 1; off < 16; off <<= 1) x += __shfl_xor(x, off);
            if (lo == 0) atomicAdd(&logit_l[rl], x);
        }
    }
    __syncthreads();

    if (tid < 32) {
        float x = logit_l[tid] + b2[0];
        float z = isNeg ? x : -x;                        // 1-sigmoid(x) = sigmoid(-x)
        float term = -logf(1.f / (1.f + expf(z)) + 1e-8f);
        #pragma unroll
        for (int off = 16; off; off >>= 1) term += __shfl_down(term, off);
        if (tid == 0) atomicAdd(acc_out, term);
    }
}

__global__ void finalize_kernel(const float* __restrict__ acc, float* __restrict__ out) {
    out[0] = acc[0] * (1.0f / (2.0f * (float)NB));
}

// ==================== launch ====================
extern "C" void kernel_launch(void* const* d_in, const int* in_sizes, int n_in,
                              void* d_out, int out_size, void* d_ws, size_t ws_size,
                              hipStream_t stream) {
    const float* vcross = (const float*)d_in[0];
    const float* tcross = (const float*)d_in[1];
    const float* vuni   = (const float*)d_in[2];
    const float* tuni   = (const float*)d_in[3];
    const float* W1     = (const float*)d_in[4];
    const float* b1     = (const float*)d_in[5];
    const float* W2     = (const float*)d_in[6];
    const float* b2     = (const float*)d_in[7];

    char* ws = (char*)d_ws;
    float* diag   = (float*)(ws + OFF_DIAG);
    int* neg      = (int*)(ws + OFF_NEG);
    int* fbrows   = (int*)(ws + OFF_FBROWS);
    float* acc    = (float*)(ws + OFF_ACC);
    int* fbcount  = (int*)(ws + OFF_ACC + 4);
    unsigned long long* fbbest = (unsigned long long*)(ws + OFF_ACC + 8);
    int* bandPart = (int*)(ws + OFF_BANDP);
    ushort_t* w1t = (ushort_t*)(ws + OFF_W1T);
    ushort_t* tb  = (ushort_t*)(ws + OFF_TB);
    ushort_t* vb  = (ushort_t*)(ws + OFF_VB);

    prep_uni_kernel<<<4096, 256, 0, stream>>>(tuni, vuni, tb, vb, diag,
                                              (uint32_t*)(ws + OFF_ACC));
    mine4_kernel<<<dim3(64, 16), 256, 0, stream>>>(tb, vb, diag, bandPart);
    combine4_kernel<<<NB / 256, 256, 0, stream>>>(bandPart, neg, fbrows, fbcount);
    fixup3_kernel<<<dim3(32, 64), 256, 0, stream>>>(tuni, vuni, fbrows, fbcount, fbbest);
    prep_head_kernel<<<2081, 256, 0, stream>>>(tcross, vcross, W1, tb, vb, w1t,
                                               fbrows, fbcount, fbbest, neg);
    head3_kernel<<<dim3(NB / 32, 2), 256, 0, stream>>>(tb, vb, w1t, neg, tcross, vcross,
                                                       W1, b1, W2, b2, acc);
    finalize_kernel<<<1, 1, 0, stream>>>(acc, (float*)d_out);
}

// Round 9
// 82.562 us; speedup vs baseline: 3.0638x; 3.0638x over previous
//
#include <hip/hip_runtime.h>
#include <stdint.h>

#define NB 8192
#define DD 256

typedef unsigned short ushort_t;
typedef __attribute__((ext_vector_type(8))) short bf16x8;
typedef __attribute__((ext_vector_type(4))) float f32x4;

// ==================== workspace layout (10014720 B <= proven 10092544) ====================
#define OFF_DIAG   0          // f32[8192]
#define OFF_NEG    32768      // int[8192]
#define OFF_MROWS  65536      // int[1024]
#define OFF_ACC    69632      // f32 acc @+0, int mcount @+4
#define OFF_BP1    73728      // u16[8][8192]   (128 KB)
#define OFF_BP2    204800     // u16[64][1024]  (128 KB)
#define OFF_FB2    335872     // u64[64][1024]  (512 KB)
#define OFF_DIAG2  847872     // f32[1024]
#define OFF_A2     851968     // bf16[1024][256] (512 KB, swizzled by slot)
#define OFF_W1T    1363968    // bf16[256][512]  (256 KB, swizzled)
#define OFF_TB     1626112    // bf16[8192][256] (4 MB, swizzled)
#define OFF_VB     5820416    // bf16[8192][256] (4 MB, swizzled) -> end 10014720

__device__ __forceinline__ unsigned short f2bf(float x) {
    uint32_t u = __float_as_uint(x);
    return (unsigned short)((u + 0x7FFFu + ((u >> 16) & 1u)) >> 16);
}

__device__ __forceinline__ uint4 packbf8(float4 x, float4 y) {
    uint4 o;
    o.x = (uint32_t)f2bf(x.x) | ((uint32_t)f2bf(x.y) << 16);
    o.y = (uint32_t)f2bf(x.z) | ((uint32_t)f2bf(x.w) << 16);
    o.z = (uint32_t)f2bf(y.x) | ((uint32_t)f2bf(y.y) << 16);
    o.w = (uint32_t)f2bf(y.z) | ((uint32_t)f2bf(y.w) << 16);
    return o;
}

__device__ __forceinline__ unsigned fkey(float s) {
    unsigned u = __float_as_uint(s);
    return (u & 0x80000000u) ? ~u : (u | 0x80000000u);
}

// ---------------- prep_uni: cvt (swizzled), diag, scalar zero-init ----------------
__global__ __launch_bounds__(256) void prep_uni_kernel(const float* __restrict__ t,
                                                       const float* __restrict__ v,
                                                       ushort_t* __restrict__ tb,
                                                       ushort_t* __restrict__ vb,
                                                       float* __restrict__ diag,
                                                       uint32_t* __restrict__ zeroRegion) {
    const int b = blockIdx.x;
    if (b < 2048) {
        const float* in = (b < 1024) ? t : v;
        ushort_t* out = (b < 1024) ? tb : vb;
        int i = (b & 1023) * 256 + threadIdx.x;     // 16B-chunk id
        int row = i >> 5, cw = i & 31, kb = cw >> 3, c = cw & 7;
        int csrc = c ^ (row & 7);
        const float4* src = (const float4*)(in + (size_t)row * DD + kb * 64 + csrc * 8);
        ((uint4*)out)[i] = packbf8(src[0], src[1]);
    } else {
        if (b == 2048 && threadIdx.x < 2) zeroRegion[threadIdx.x] = 0;   // acc + mcount
        int row = (b - 2048) * 4 + (threadIdx.x >> 6);
        int lane = threadIdx.x & 63;
        float4 a = *(const float4*)(t + (size_t)row * DD + lane * 4);
        float4 bb = *(const float4*)(v + (size_t)row * DD + lane * 4);
        float s = a.x * bb.x + a.y * bb.y + a.z * bb.z + a.w * bb.w;
        #pragma unroll
        for (int off = 32; off; off >>= 1) s += __shfl_down(s, off);
        if (lane == 0) diag[row] = s;
    }
}

// ---------------- shared B-staging (proven R7) ----------------
__device__ __forceinline__ void stage_b(const ushort_t* __restrict__ VB, ushort_t* Bs,
                                        int colBase, int kc, int tid) {
    #pragma unroll
    for (int i = 0; i < 4; ++i) {
        int idx = i * 256 + tid;              // 0..1023
        int r = idx >> 3, c8 = idx & 7;       // source pre-swizzled -> linear copy
        __builtin_amdgcn_global_load_lds(
            (const __attribute__((address_space(1))) uint32_t*)(VB + (size_t)(colBase + r) * DD + kc + c8 * 8),
            (__attribute__((address_space(3))) uint32_t*)(Bs + idx * 8), 16, 0, 0);
    }
}

// ---------------- mine_p1: prefix cols [0,1024), mine3 structure (proven R7) ----------------
__global__ __launch_bounds__(256, 4) void mine_p1_kernel(const ushort_t* __restrict__ TB,
                                                         const ushort_t* __restrict__ VB,
                                                         const float* __restrict__ diag,
                                                         ushort_t* __restrict__ bp1) {
    __shared__ ushort_t Bs[2][128 * 64];       // 32 KB
    __shared__ float diag_s[128];

    const int tid = threadIdx.x;
    const int rowBase = blockIdx.x * 128;
    const int colBase = blockIdx.y * 128;      // y < 8
    const int lane = tid & 63;
    const int wave = tid >> 6;
    const int wr = wave >> 1, wc = wave & 1;
    const int lo = lane & 15, hi = lane >> 4;
    const int lx = lo & 7;

    if (tid < 128) diag_s[tid] = diag[rowBase + tid];

    f32x4 acc[4][4];
    #pragma unroll
    for (int m = 0; m < 4; m++)
        #pragma unroll
        for (int n = 0; n < 4; n++) acc[m][n] = (f32x4){0.f, 0.f, 0.f, 0.f};

    const ushort_t* Abase = TB + (size_t)(rowBase + wr * 64 + lo) * DD;

    stage_b(VB, Bs[0], colBase, 0, tid);
    __syncthreads();

    for (int kt = 0; kt < 4; ++kt) {
        const int buf = kt & 1;
        if (kt < 3)
            stage_b(VB, Bs[buf ^ 1], colBase, (kt + 1) * 64, tid);
        #pragma unroll
        for (int ksl = 0; ksl < 2; ksl++) {
            const int ch = ((((ksl << 2) | hi) ^ lx) << 3);
            bf16x8 a[4], b[4];
            #pragma unroll
            for (int m = 0; m < 4; m++)
                a[m] = *(const bf16x8*)(Abase + (size_t)m * 16 * DD + kt * 64 + ch);
            #pragma unroll
            for (int n = 0; n < 4; n++)
                b[n] = *(const bf16x8*)&Bs[buf][(wc * 64 + n * 16 + lo) * 64 + ch];
            #pragma unroll
            for (int m = 0; m < 4; m++)
                #pragma unroll
                for (int n = 0; n < 4; n++)
                    acc[m][n] = __builtin_amdgcn_mfma_f32_16x16x32_bf16(a[m], b[n], acc[m][n], 0, 0, 0);
        }
        __syncthreads();
    }

    // epilogue: band-min, plain u16 partial store (block owns rows x colGroup)
    #pragma unroll
    for (int m = 0; m < 4; m++) {
        #pragma unroll
        for (int q = 0; q < 4; q++) {
            const int rl = wr * 64 + m * 16 + hi * 4 + q;
            const int grow = rowBase + rl;
            const float c0 = diag_s[rl] - 0.35f;
            int bm = 0x7FFFFFFF;
            #pragma unroll
            for (int n = 0; n < 4; n++) {
                const float tt = acc[m][n][q] - c0;
                const int gcol = colBase + wc * 64 + n * 16 + lo;
                int cand = (fabsf(tt) < 0.15f && gcol != grow) ? gcol : 0x7FFFFFFF;
                bm = min(bm, cand);
            }
            #pragma unroll
            for (int off = 1; off < 16; off <<= 1) bm = min(bm, __shfl_xor(bm, off));
            if (lo == 0)
                bp1[blockIdx.y * NB + grow] = (ushort_t)min(bm, 0xFFFF);
        }
    }
}

// ---------------- combine_p1: prefix min; collect missing rows (cap 1024) ----------------
__global__ __launch_bounds__(256) void combine_p1_kernel(const ushort_t* __restrict__ bp1,
                                                         int* __restrict__ neg,
                                                         int* __restrict__ mrows,
                                                         int* __restrict__ mcount) {
    int row = blockIdx.x * 256 + threadIdx.x;
    int bmin = 0xFFFF;
    #pragma unroll
    for (int g = 0; g < 8; g++) bmin = min(bmin, (int)bp1[g * NB + row]);
    if (bmin < 0xFFFF) {
        neg[row] = bmin;
    } else {
        neg[row] = (row + 4096) & (NB - 1);     // placeholder, overwritten by combine_p2
        int i = atomicAdd(mcount, 1);
        if (i < 1024) mrows[i] = row;
    }
}

// ---------------- gather_p2: compact missing rows -> A2 (re-keyed swizzle), diag2 ----------------
__global__ __launch_bounds__(256) void gather_p2_kernel(const ushort_t* __restrict__ TB,
                                                        const float* __restrict__ diag,
                                                        const int* __restrict__ mrows,
                                                        const int* __restrict__ mcount,
                                                        ushort_t* __restrict__ A2,
                                                        float* __restrict__ diag2) {
    const int count = min(mcount[0], 1024);
    int idx = blockIdx.x * 256 + threadIdx.x;   // 16384 threads
    #pragma unroll
    for (int u = 0; u < 2; u++) {
        int t = idx * 2 + u;                    // chunk-copy id, 0..32767
        int s = t >> 5, c = t & 31;             // slot, 16B chunk
        int kb = c >> 3, cc = c & 7;
        uint4 val = {0, 0, 0, 0};
        if (s < count) {
            int r = mrows[s];
            int csrc = cc ^ ((s ^ r) & 7);      // re-key swizzle: tb keyed by r&7 -> A2 keyed by s&7
            val = *(const uint4*)(TB + (size_t)r * DD + kb * 64 + csrc * 8);
        }
        *(uint4*)(A2 + (size_t)s * DD + kb * 64 + cc * 8) = val;
    }
    if (idx < 1024) diag2[idx] = (idx < count) ? diag[mrows[idx]] : 0.f;
}

// ---------------- mine_p2: missing rows x all cols; band-min + argmax fallback ----------------
__global__ __launch_bounds__(256, 3) void mine_p2_kernel(const ushort_t* __restrict__ A2,
                                                         const ushort_t* __restrict__ VB,
                                                         const float* __restrict__ diag2,
                                                         const int* __restrict__ mrows,
                                                         const int* __restrict__ mcount,
                                                         ushort_t* __restrict__ bp2,
                                                         unsigned long long* __restrict__ fb2) {
    const int slotBase = blockIdx.x * 128;
    const int count = min(mcount[0], 1024);
    if (slotBase >= count) return;              // uniform early-out for inactive panels

    __shared__ ushort_t Bs[2][128 * 64];
    __shared__ float diag_s[128];
    __shared__ int rows_s[128];

    const int tid = threadIdx.x;
    const int colBase = blockIdx.y * 128;       // y < 64
    const int lane = tid & 63;
    const int wave = tid >> 6;
    const int wr = wave >> 1, wc = wave & 1;
    const int lo = lane & 15, hi = lane >> 4;
    const int lx = lo & 7;

    if (tid < 128) {
        diag_s[tid] = diag2[slotBase + tid];
        rows_s[tid] = mrows[slotBase + tid];    // garbage for pad slots; results discarded
    }

    f32x4 acc[4][4];
    #pragma unroll
    for (int m = 0; m < 4; m++)
        #pragma unroll
        for (int n = 0; n < 4; n++) acc[m][n] = (f32x4){0.f, 0.f, 0.f, 0.f};

    const ushort_t* Abase = A2 + (size_t)(slotBase + wr * 64 + lo) * DD;

    stage_b(VB, Bs[0], colBase, 0, tid);
    __syncthreads();

    for (int kt = 0; kt < 4; ++kt) {
        const int buf = kt & 1;
        if (kt < 3)
            stage_b(VB, Bs[buf ^ 1], colBase, (kt + 1) * 64, tid);
        #pragma unroll
        for (int ksl = 0; ksl < 2; ksl++) {
            const int ch = ((((ksl << 2) | hi) ^ lx) << 3);
            bf16x8 a[4], b[4];
            #pragma unroll
            for (int m = 0; m < 4; m++)
                a[m] = *(const bf16x8*)(Abase + (size_t)m * 16 * DD + kt * 64 + ch);
            #pragma unroll
            for (int n = 0; n < 4; n++)
                b[n] = *(const bf16x8*)&Bs[buf][(wc * 64 + n * 16 + lo) * 64 + ch];
            #pragma unroll
            for (int m = 0; m < 4; m++)
                #pragma unroll
                for (int n = 0; n < 4; n++)
                    acc[m][n] = __builtin_amdgcn_mfma_f32_16x16x32_bf16(a[m], b[n], acc[m][n], 0, 0, 0);
        }
        __syncthreads();
    }

    // epilogue: band-min + packed argmax (tie-break smallest col), plain partial stores
    #pragma unroll
    for (int m = 0; m < 4; m++) {
        #pragma unroll
        for (int q = 0; q < 4; q++) {
            const int rl = wr * 64 + m * 16 + hi * 4 + q;
            const int actual = rows_s[rl];
            const float c0 = diag_s[rl] - 0.35f;
            int bm = 0x7FFFFFFF;
            unsigned long long pk = 0ULL;
            #pragma unroll
            for (int n = 0; n < 4; n++) {
                const float s = acc[m][n][q];
                const int gcol = colBase + wc * 64 + n * 16 + lo;
                if (gcol != actual) {
                    unsigned long long p = ((unsigned long long)fkey(s) << 32) | (unsigned)(NB - 1 - gcol);
                    pk = (p > pk) ? p : pk;
                    if (fabsf(s - c0) < 0.15f) bm = min(bm, gcol);
                }
            }
            #pragma unroll
            for (int off = 1; off < 16; off <<= 1) {
                unsigned long long po = __shfl_xor(pk, off);
                int bo = __shfl_xor(bm, off);
                pk = (po > pk) ? po : pk;
                bm = min(bm, bo);
            }
            if (lo == 0) {
                bp2[blockIdx.y * 1024 + slotBase + rl] = (ushort_t)min(bm, 0xFFFF);
                fb2[blockIdx.y * 1024 + slotBase + rl] = pk;
            }
        }
    }
}

// ---------------- combine_p2: finalize missing rows ----------------
__global__ __launch_bounds__(256) void combine_p2_kernel(const ushort_t* __restrict__ bp2,
                                                         const unsigned long long* __restrict__ fb2,
                                                         const int* __restrict__ mrows,
                                                         const int* __restrict__ mcount,
                                                         int* __restrict__ neg) {
    int s = blockIdx.x * 256 + threadIdx.x;     // grid 4 -> 1024 slots
    const int count = min(mcount[0], 1024);
    if (s >= count) return;
    int bmin = 0xFFFF;
    unsigned long long pk = 0ULL;
    for (int g = 0; g < 64; g++) {
        bmin = min(bmin, (int)bp2[g * 1024 + s]);
        unsigned long long f = fb2[g * 1024 + s];
        pk = (f > pk) ? f : pk;
    }
    neg[mrows[s]] = (bmin < 0xFFFF) ? bmin : (NB - 1 - (int)(unsigned)(pk & 0xFFFFFFFFull));
}

// ---------------- prep_head: cvt tcross/vcross, W1T (all swizzled) ----------------
__global__ __launch_bounds__(256) void prep_head_kernel(const float* __restrict__ tcross,
                                                        const float* __restrict__ vcross,
                                                        const float* __restrict__ W1,
                                                        ushort_t* __restrict__ tb,
                                                        ushort_t* __restrict__ vb,
                                                        ushort_t* __restrict__ W1T) {
    const int b = blockIdx.x;
    const int tid = threadIdx.x;
    if (b < 2048) {
        const float* in = (b < 1024) ? tcross : vcross;
        ushort_t* out = (b < 1024) ? tb : vb;
        int i = (b & 1023) * 256 + tid;
        int row = i >> 5, cw = i & 31, kb = cw >> 3, c = cw & 7;
        int csrc = c ^ (row & 7);
        const float4* src = (const float4*)(in + (size_t)row * DD + kb * 64 + csrc * 8);
        ((uint4*)out)[i] = packbf8(src[0], src[1]);
    } else {
        // W1T[n][k] = bf16(W1[k][n]), chunk-swizzled by n&7 within each 64-k block
        __shared__ float Ls[64][68];
        int tt = b - 2048;                      // 0..31
        int kb = tt >> 2, nb = tt & 3;
        int r = tid >> 2, q4 = tid & 3;
        #pragma unroll
        for (int j = 0; j < 4; j++) {
            float4 x = *(const float4*)(W1 + (size_t)(kb * 64 + r) * DD + nb * 64 + q4 * 16 + j * 4);
            *(float4*)&Ls[r][q4 * 16 + j * 4] = x;
        }
        __syncthreads();
        int rn = tid >> 2, cq = (tid & 3) * 2;
        #pragma unroll
        for (int cc = 0; cc < 2; cc++) {
            int c = cq + cc;
            int csrc = c ^ (rn & 7);
            float4 x, y;
            x.x = Ls[csrc * 8 + 0][rn]; x.y = Ls[csrc * 8 + 1][rn];
            x.z = Ls[csrc * 8 + 2][rn]; x.w = Ls[csrc * 8 + 3][rn];
            y.x = Ls[csrc * 8 + 4][rn]; y.y = Ls[csrc * 8 + 5][rn];
            y.z = Ls[csrc * 8 + 6][rn]; y.w = Ls[csrc * 8 + 7][rn];
            *(uint4*)&W1T[(size_t)(nb * 64 + rn) * 512 + kb * 64 + c * 8] = packbf8(x, y);
        }
    }
}

// ==================== MFMA ITM head (proven R7) ====================
__device__ __forceinline__ void stage_head(const ushort_t* __restrict__ TCB,
                                           const ushort_t* __restrict__ VCB,
                                           const int* __restrict__ neg, int isNeg,
                                           const ushort_t* __restrict__ W1T,
                                           ushort_t* As, ushort_t* Bs,
                                           int rowBase, int kc, int tid) {
    #pragma unroll
    for (int i = 0; i < 2; ++i) {                 // A: 64 rows x 64 k
        int idx = i * 256 + tid;
        int r = idx >> 3, c8 = idx & 7;
        const ushort_t* src;
        if (kc < 256) {
            src = TCB + (size_t)(rowBase + r) * DD + kc + c8 * 8;
        } else {
            int rr = isNeg ? neg[rowBase + r] : (rowBase + r);
            int cs = c8 ^ ((r ^ rr) & 7);          // re-key rr&7 -> r&7
            src = VCB + (size_t)rr * DD + (kc - 256) + cs * 8;
        }
        __builtin_amdgcn_global_load_lds(
            (const __attribute__((address_space(1))) uint32_t*)src,
            (__attribute__((address_space(3))) uint32_t*)(As + idx * 8), 16, 0, 0);
    }
    #pragma unroll
    for (int i = 0; i < 8; ++i) {                 // B: 256 cols x 64 k (W1T pre-swizzled)
        int idx = i * 256 + tid;
        int n = idx >> 3, c8 = idx & 7;
        __builtin_amdgcn_global_load_lds(
            (const __attribute__((address_space(1))) uint32_t*)(W1T + (size_t)n * 512 + kc + c8 * 8),
            (__attribute__((address_space(3))) uint32_t*)(Bs + idx * 8), 16, 0, 0);
    }
}

__global__ __launch_bounds__(256) void head2_kernel(const ushort_t* __restrict__ TCB,
                                                    const ushort_t* __restrict__ VCB,
                                                    const ushort_t* __restrict__ W1T,
                                                    const int* __restrict__ neg,
                                                    const float* __restrict__ tcf,
                                                    const float* __restrict__ vcf,
                                                    const float* __restrict__ W1,
                                                    const float* __restrict__ b1,
                                                    const float* __restrict__ W2,
                                                    const float* __restrict__ b2,
                                                    float* __restrict__ acc_out) {
    __shared__ ushort_t As[2][64 * 64];
    __shared__ ushort_t Bs[2][256 * 64];
    __shared__ float dot_l[64];
    __shared__ float logit_l[64];

    const int tid = threadIdx.x;
    const int rowBase = blockIdx.x * 64;
    const int isNeg = blockIdx.y;
    const int lane = tid & 63;
    const int wcv = tid >> 6;
    const int lo = lane & 15, hi = lane >> 4;
    const int lx = lo & 7;

    // inline dot feature (fp32 exact): 4 threads per row
    {
        int r = tid >> 2, quarter = tid & 3;
        int grow = rowBase + r;
        int vrow = isNeg ? neg[grow] : grow;
        const float4* tp = (const float4*)(tcf + (size_t)grow * DD + quarter * 64);
        const float4* vp = (const float4*)(vcf + (size_t)vrow * DD + quarter * 64);
        float sd = 0.f;
        #pragma unroll
        for (int j = 0; j < 16; j++) {
            float4 a = tp[j], v = vp[j];
            sd += a.x * v.x + a.y * v.y + a.z * v.z + a.w * v.w;
        }
        sd += __shfl_xor(sd, 1);
        sd += __shfl_xor(sd, 2);
        if (quarter == 0) dot_l[r] = sd;
        if (tid < 64) logit_l[tid] = 0.f;
    }

    f32x4 acc[4][4];
    #pragma unroll
    for (int m = 0; m < 4; m++)
        #pragma unroll
        for (int n = 0; n < 4; n++) acc[m][n] = (f32x4){0.f, 0.f, 0.f, 0.f};

    stage_head(TCB, VCB, neg, isNeg, W1T, As[0], Bs[0], rowBase, 0, tid);
    __syncthreads();

    for (int kt = 0; kt < 8; ++kt) {
        const int buf = kt & 1;
        if (kt < 7)
            stage_head(TCB, VCB, neg, isNeg, W1T, As[buf ^ 1], Bs[buf ^ 1], rowBase, (kt + 1) * 64, tid);
        #pragma unroll
        for (int ksl = 0; ksl < 2; ksl++) {
            const int ch = ((((ksl << 2) | hi) ^ lx) << 3);
            bf16x8 a[4], b[4];
            #pragma unroll
            for (int m = 0; m < 4; m++)
                a[m] = *(const bf16x8*)&As[buf][(m * 16 + lo) * 64 + ch];
            #pragma unroll
            for (int n = 0; n < 4; n++)
                b[n] = *(const bf16x8*)&Bs[buf][(wcv * 64 + n * 16 + lo) * 64 + ch];
            #pragma unroll
            for (int m = 0; m < 4; m++)
                #pragma unroll
                for (int n = 0; n < 4; n++)
                    acc[m][n] = __builtin_amdgcn_mfma_f32_16x16x32_bf16(a[m], b[n], acc[m][n], 0, 0, 0);
        }
        __syncthreads();
    }

    float b1v[4], w5v[4], w2v[4];
    #pragma unroll
    for (int n = 0; n < 4; n++) {
        int cl = wcv * 64 + n * 16 + lo;
        b1v[n] = b1[cl];
        w5v[n] = W1[(size_t)512 * DD + cl];
        w2v[n] = W2[cl];
    }
    #pragma unroll
    for (int m = 0; m < 4; m++) {
        #pragma unroll
        for (int q = 0; q < 4; q++) {
            const int rl = m * 16 + hi * 4 + q;
            const float dt = dot_l[rl];
            float x = 0.f;
            #pragma unroll
            for (int n = 0; n < 4; n++) {
                float h = acc[m][n][q] + b1v[n] + dt * w5v[n];
                x += fmaxf(h, 0.f) * w2v[n];
            }
            #pragma unroll
            for (int off = 1; off < 16; off <<= 1) x += __shfl_xor(x, off);
            if (lo == 0) atomicAdd(&logit_l[rl], x);
        }
    }
    __syncthreads();

    if (tid < 64) {
        float x = logit_l[tid] + b2[0];
        float z = isNeg ? x : -x;                        // 1-sigmoid(x) = sigmoid(-x)
        float term = -logf(1.f / (1.f + expf(z)) + 1e-8f);
        #pragma unroll
        for (int off = 32; off; off >>= 1) term += __shfl_down(term, off);
        if (tid == 0) atomicAdd(acc_out, term);
    }
}

__global__ void finalize_kernel(const float* __restrict__ acc, float* __restrict__ out) {
    out[0] = acc[0] * (1.0f / (2.0f * (float)NB));
}

// ==================== launch ====================
extern "C" void kernel_launch(void* const* d_in, const int* in_sizes, int n_in,
                              void* d_out, int out_size, void* d_ws, size_t ws_size,
                              hipStream_t stream) {
    const float* vcross = (const float*)d_in[0];
    const float* tcross = (const float*)d_in[1];
    const float* vuni   = (const float*)d_in[2];
    const float* tuni   = (const float*)d_in[3];
    const float* W1     = (const float*)d_in[4];
    const float* b1     = (const float*)d_in[5];
    const float* W2     = (const float*)d_in[6];
    const float* b2     = (const float*)d_in[7];

    char* ws = (char*)d_ws;
    float* diag   = (float*)(ws + OFF_DIAG);
    int* neg      = (int*)(ws + OFF_NEG);
    int* mrows    = (int*)(ws + OFF_MROWS);
    float* acc    = (float*)(ws + OFF_ACC);
    int* mcount   = (int*)(ws + OFF_ACC + 4);
    ushort_t* bp1 = (ushort_t*)(ws + OFF_BP1);
    ushort_t* bp2 = (ushort_t*)(ws + OFF_BP2);
    unsigned long long* fb2 = (unsigned long long*)(ws + OFF_FB2);
    float* diag2  = (float*)(ws + OFF_DIAG2);
    ushort_t* A2  = (ushort_t*)(ws + OFF_A2);
    ushort_t* w1t = (ushort_t*)(ws + OFF_W1T);
    ushort_t* tb  = (ushort_t*)(ws + OFF_TB);
    ushort_t* vb  = (ushort_t*)(ws + OFF_VB);

    prep_uni_kernel<<<4096, 256, 0, stream>>>(tuni, vuni, tb, vb, diag,
                                              (uint32_t*)(ws + OFF_ACC));
    mine_p1_kernel<<<dim3(64, 8), 256, 0, stream>>>(tb, vb, diag, bp1);
    combine_p1_kernel<<<NB / 256, 256, 0, stream>>>(bp1, neg, mrows, mcount);
    gather_p2_kernel<<<64, 256, 0, stream>>>(tb, diag, mrows, mcount, A2, diag2);
    mine_p2_kernel<<<dim3(8, 64), 256, 0, stream>>>(A2, vb, diag2, mrows, mcount, bp2, fb2);
    combine_p2_kernel<<<4, 256, 0, stream>>>(bp2, fb2, mrows, mcount, neg);
    prep_head_kernel<<<2080, 256, 0, stream>>>(tcross, vcross, W1, tb, vb, w1t);
    head2_kernel<<<dim3(NB / 64, 2), 256, 0, stream>>>(tb, vb, w1t, neg, tcross, vcross,
                                                       W1, b1, W2, b2, acc);
    finalize_kernel<<<1, 1, 0, stream>>>(acc, (float*)d_out);
}

// Round 11
// 81.992 us; speedup vs baseline: 3.0851x; 1.0070x over previous
//
#include <hip/hip_runtime.h>
#include <stdint.h>

#define NB 8192
#define DD 256

typedef unsigned short ushort_t;
typedef __attribute__((ext_vector_type(8))) short bf16x8;
typedef __attribute__((ext_vector_type(4))) float f32x4;

// ==================== workspace layout (10039296 B <= proven 10092544) ====================
#define OFF_DIAG   0          // f32[8192]
#define OFF_NEG    32768      // int[8192]
#define OFF_MROWS  65536      // int[1024]
#define OFF_ACC    69632      // f32 acc @+0, int mcount @+4
#define OFF_BP1    73728      // u16[8][8192]   (128 KB)
#define OFF_BP2    204800     // u16[64][1024]  (128 KB)
#define OFF_FB2    335872     // u64[64][1024]  (512 KB) -> ends 860160 (no overlap now)
#define OFF_DIAG2  860160     // f32[1024]
#define OFF_A2     864256     // bf16[1024][256] (512 KB, swizzled by slot)
#define OFF_W1T    1388544    // bf16[256][512]  (256 KB, swizzled)
#define OFF_TB     1650688    // bf16[8192][256] (4 MB, swizzled)
#define OFF_VB     5844992    // bf16[8192][256] (4 MB, swizzled) -> end 10039296

__device__ __forceinline__ unsigned short f2bf(float x) {
    uint32_t u = __float_as_uint(x);
    return (unsigned short)((u + 0x7FFFu + ((u >> 16) & 1u)) >> 16);
}

__device__ __forceinline__ uint4 packbf8(float4 x, float4 y) {
    uint4 o;
    o.x = (uint32_t)f2bf(x.x) | ((uint32_t)f2bf(x.y) << 16);
    o.y = (uint32_t)f2bf(x.z) | ((uint32_t)f2bf(x.w) << 16);
    o.z = (uint32_t)f2bf(y.x) | ((uint32_t)f2bf(y.y) << 16);
    o.w = (uint32_t)f2bf(y.z) | ((uint32_t)f2bf(y.w) << 16);
    return o;
}

__device__ __forceinline__ unsigned fkey(float s) {
    unsigned u = __float_as_uint(s);
    return (u & 0x80000000u) ? ~u : (u | 0x80000000u);
}

// ---------------- prep_uni: cvt uni (swizzled), diag, W1T, zero-init ----------------
__global__ __launch_bounds__(256) void prep_uni_kernel(const float* __restrict__ t,
                                                       const float* __restrict__ v,
                                                       const float* __restrict__ W1,
                                                       ushort_t* __restrict__ tb,
                                                       ushort_t* __restrict__ vb,
                                                       ushort_t* __restrict__ W1T,
                                                       float* __restrict__ diag,
                                                       uint32_t* __restrict__ zeroRegion) {
    const int b = blockIdx.x;
    const int tid = threadIdx.x;
    if (b < 2048) {
        const float* in = (b < 1024) ? t : v;
        ushort_t* out = (b < 1024) ? tb : vb;
        int i = (b & 1023) * 256 + tid;             // 16B-chunk id
        int row = i >> 5, cw = i & 31, kb = cw >> 3, c = cw & 7;
        int csrc = c ^ (row & 7);
        const float4* src = (const float4*)(in + (size_t)row * DD + kb * 64 + csrc * 8);
        ((uint4*)out)[i] = packbf8(src[0], src[1]);
    } else if (b < 4096) {
        if (b == 2048 && tid < 2) zeroRegion[tid] = 0;   // acc + mcount
        int row = (b - 2048) * 4 + (tid >> 6);
        int lane = tid & 63;
        float4 a = *(const float4*)(t + (size_t)row * DD + lane * 4);
        float4 bb = *(const float4*)(v + (size_t)row * DD + lane * 4);
        float s = a.x * bb.x + a.y * bb.y + a.z * bb.z + a.w * bb.w;
        #pragma unroll
        for (int off = 32; off; off >>= 1) s += __shfl_down(s, off);
        if (lane == 0) diag[row] = s;
    } else {
        // W1T[n][k] = bf16(W1[k][n]), chunk-swizzled by n&7 within each 64-k block
        __shared__ float Ls[64][68];
        int tt = b - 4096;                          // 0..31
        int kb = tt >> 2, nb = tt & 3;
        int r = tid >> 2, q4 = tid & 3;
        #pragma unroll
        for (int j = 0; j < 4; j++) {
            float4 x = *(const float4*)(W1 + (size_t)(kb * 64 + r) * DD + nb * 64 + q4 * 16 + j * 4);
            *(float4*)&Ls[r][q4 * 16 + j * 4] = x;
        }
        __syncthreads();
        int rn = tid >> 2, cq = (tid & 3) * 2;
        #pragma unroll
        for (int cc = 0; cc < 2; cc++) {
            int c = cq + cc;
            int csrc = c ^ (rn & 7);
            float4 x, y;
            x.x = Ls[csrc * 8 + 0][rn]; x.y = Ls[csrc * 8 + 1][rn];
            x.z = Ls[csrc * 8 + 2][rn]; x.w = Ls[csrc * 8 + 3][rn];
            y.x = Ls[csrc * 8 + 4][rn]; y.y = Ls[csrc * 8 + 5][rn];
            y.z = Ls[csrc * 8 + 6][rn]; y.w = Ls[csrc * 8 + 7][rn];
            *(uint4*)&W1T[(size_t)(nb * 64 + rn) * 512 + kb * 64 + c * 8] = packbf8(x, y);
        }
    }
}

// ---------------- shared B-staging (proven R7) ----------------
__device__ __forceinline__ void stage_b(const ushort_t* __restrict__ VB, ushort_t* Bs,
                                        int colBase, int kc, int tid) {
    #pragma unroll
    for (int i = 0; i < 4; ++i) {
        int idx = i * 256 + tid;              // 0..1023
        int r = idx >> 3, c8 = idx & 7;       // source pre-swizzled -> linear copy
        __builtin_amdgcn_global_load_lds(
            (const __attribute__((address_space(1))) uint32_t*)(VB + (size_t)(colBase + r) * DD + kc + c8 * 8),
            (__attribute__((address_space(3))) uint32_t*)(Bs + idx * 8), 16, 0, 0);
    }
}

// ---------------- mine_p1: prefix cols [0,1024) (proven R9) ----------------
__global__ __launch_bounds__(256, 4) void mine_p1_kernel(const ushort_t* __restrict__ TB,
                                                         const ushort_t* __restrict__ VB,
                                                         const float* __restrict__ diag,
                                                         ushort_t* __restrict__ bp1) {
    __shared__ ushort_t Bs[2][128 * 64];       // 32 KB
    __shared__ float diag_s[128];

    const int tid = threadIdx.x;
    const int rowBase = blockIdx.x * 128;
    const int colBase = blockIdx.y * 128;      // y < 8
    const int lane = tid & 63;
    const int wave = tid >> 6;
    const int wr = wave >> 1, wc = wave & 1;
    const int lo = lane & 15, hi = lane >> 4;
    const int lx = lo & 7;

    if (tid < 128) diag_s[tid] = diag[rowBase + tid];

    f32x4 acc[4][4];
    #pragma unroll
    for (int m = 0; m < 4; m++)
        #pragma unroll
        for (int n = 0; n < 4; n++) acc[m][n] = (f32x4){0.f, 0.f, 0.f, 0.f};

    const ushort_t* Abase = TB + (size_t)(rowBase + wr * 64 + lo) * DD;

    stage_b(VB, Bs[0], colBase, 0, tid);
    __syncthreads();

    for (int kt = 0; kt < 4; ++kt) {
        const int buf = kt & 1;
        if (kt < 3)
            stage_b(VB, Bs[buf ^ 1], colBase, (kt + 1) * 64, tid);
        #pragma unroll
        for (int ksl = 0; ksl < 2; ksl++) {
            const int ch = ((((ksl << 2) | hi) ^ lx) << 3);
            bf16x8 a[4], b[4];
            #pragma unroll
            for (int m = 0; m < 4; m++)
                a[m] = *(const bf16x8*)(Abase + (size_t)m * 16 * DD + kt * 64 + ch);
            #pragma unroll
            for (int n = 0; n < 4; n++)
                b[n] = *(const bf16x8*)&Bs[buf][(wc * 64 + n * 16 + lo) * 64 + ch];
            #pragma unroll
            for (int m = 0; m < 4; m++)
                #pragma unroll
                for (int n = 0; n < 4; n++)
                    acc[m][n] = __builtin_amdgcn_mfma_f32_16x16x32_bf16(a[m], b[n], acc[m][n], 0, 0, 0);
        }
        __syncthreads();
    }

    #pragma unroll
    for (int m = 0; m < 4; m++) {
        #pragma unroll
        for (int q = 0; q < 4; q++) {
            const int rl = wr * 64 + m * 16 + hi * 4 + q;
            const int grow = rowBase + rl;
            const float c0 = diag_s[rl] - 0.35f;
            int bm = 0x7FFFFFFF;
            #pragma unroll
            for (int n = 0; n < 4; n++) {
                const float tt = acc[m][n][q] - c0;
                const int gcol = colBase + wc * 64 + n * 16 + lo;
                int cand = (fabsf(tt) < 0.15f && gcol != grow) ? gcol : 0x7FFFFFFF;
                bm = min(bm, cand);
            }
            #pragma unroll
            for (int off = 1; off < 16; off <<= 1) bm = min(bm, __shfl_xor(bm, off));
            if (lo == 0)
                bp1[blockIdx.y * NB + grow] = (ushort_t)min(bm, 0xFFFF);
        }
    }
}

// ---------------- combine_p1: prefix min; collect missing rows (cap 1024) ----------------
__global__ __launch_bounds__(256) void combine_p1_kernel(const ushort_t* __restrict__ bp1,
                                                         int* __restrict__ neg,
                                                         int* __restrict__ mrows,
                                                         int* __restrict__ mcount) {
    int row = blockIdx.x * 256 + threadIdx.x;
    int bmin = 0xFFFF;
    #pragma unroll
    for (int g = 0; g < 8; g++) bmin = min(bmin, (int)bp1[g * NB + row]);
    if (bmin < 0xFFFF) {
        neg[row] = bmin;
    } else {
        neg[row] = (row + 4096) & (NB - 1);     // placeholder, overwritten by combine_p2
        int i = atomicAdd(mcount, 1);
        if (i < 1024) mrows[i] = row;
    }
}

// ---------------- gather_p2: compact missing rows -> A2 (re-keyed swizzle), diag2 ----------------
__global__ __launch_bounds__(256) void gather_p2_kernel(const ushort_t* __restrict__ TB,
                                                        const float* __restrict__ diag,
                                                        const int* __restrict__ mrows,
                                                        const int* __restrict__ mcount,
                                                        ushort_t* __restrict__ A2,
                                                        float* __restrict__ diag2) {
    const int count = min(mcount[0], 1024);
    int idx = blockIdx.x * 256 + threadIdx.x;   // 16384 threads
    #pragma unroll
    for (int u = 0; u < 2; u++) {
        int t = idx * 2 + u;                    // chunk-copy id, 0..32767
        int s = t >> 5, c = t & 31;             // slot, 16B chunk
        int kb = c >> 3, cc = c & 7;
        uint4 val = {0, 0, 0, 0};
        if (s < count) {
            int r = mrows[s];
            int csrc = cc ^ ((s ^ r) & 7);      // re-key swizzle: tb keyed by r&7 -> A2 keyed by s&7
            val = *(const uint4*)(TB + (size_t)r * DD + kb * 64 + csrc * 8);
        }
        *(uint4*)(A2 + (size_t)s * DD + kb * 64 + cc * 8) = val;
    }
    if (idx < 1024) diag2[idx] = (idx < count) ? diag[mrows[idx]] : 0.f;
}

// ---------------- mine_p2: missing rows x all cols; band-min + argmax fallback ----------------
__global__ __launch_bounds__(256, 3) void mine_p2_kernel(const ushort_t* __restrict__ A2,
                                                         const ushort_t* __restrict__ VB,
                                                         const float* __restrict__ diag2,
                                                         const int* __restrict__ mrows,
                                                         const int* __restrict__ mcount,
                                                         ushort_t* __restrict__ bp2,
                                                         unsigned long long* __restrict__ fb2) {
    const int slotBase = blockIdx.x * 128;
    const int count = min(mcount[0], 1024);
    if (slotBase >= count) return;              // uniform early-out for inactive panels

    __shared__ ushort_t Bs[2][128 * 64];
    __shared__ float diag_s[128];
    __shared__ int rows_s[128];

    const int tid = threadIdx.x;
    const int colBase = blockIdx.y * 128;       // y < 64
    const int lane = tid & 63;
    const int wave = tid >> 6;
    const int wr = wave >> 1, wc = wave & 1;
    const int lo = lane & 15, hi = lane >> 4;
    const int lx = lo & 7;

    if (tid < 128) {
        diag_s[tid] = diag2[slotBase + tid];
        rows_s[tid] = mrows[slotBase + tid];    // garbage for pad slots; results discarded
    }

    f32x4 acc[4][4];
    #pragma unroll
    for (int m = 0; m < 4; m++)
        #pragma unroll
        for (int n = 0; n < 4; n++) acc[m][n] = (f32x4){0.f, 0.f, 0.f, 0.f};

    const ushort_t* Abase = A2 + (size_t)(slotBase + wr * 64 + lo) * DD;

    stage_b(VB, Bs[0], colBase, 0, tid);
    __syncthreads();

    for (int kt = 0; kt < 4; ++kt) {
        const int buf = kt & 1;
        if (kt < 3)
            stage_b(VB, Bs[buf ^ 1], colBase, (kt + 1) * 64, tid);
        #pragma unroll
        for (int ksl = 0; ksl < 2; ksl++) {
            const int ch = ((((ksl << 2) | hi) ^ lx) << 3);
            bf16x8 a[4], b[4];
            #pragma unroll
            for (int m = 0; m < 4; m++)
                a[m] = *(const bf16x8*)(Abase + (size_t)m * 16 * DD + kt * 64 + ch);
            #pragma unroll
            for (int n = 0; n < 4; n++)
                b[n] = *(const bf16x8*)&Bs[buf][(wc * 64 + n * 16 + lo) * 64 + ch];
            #pragma unroll
            for (int m = 0; m < 4; m++)
                #pragma unroll
                for (int n = 0; n < 4; n++)
                    acc[m][n] = __builtin_amdgcn_mfma_f32_16x16x32_bf16(a[m], b[n], acc[m][n], 0, 0, 0);
        }
        __syncthreads();
    }

    #pragma unroll
    for (int m = 0; m < 4; m++) {
        #pragma unroll
        for (int q = 0; q < 4; q++) {
            const int rl = wr * 64 + m * 16 + hi * 4 + q;
            const int actual = rows_s[rl];
            const float c0 = diag_s[rl] - 0.35f;
            int bm = 0x7FFFFFFF;
            unsigned long long pk = 0ULL;
            #pragma unroll
            for (int n = 0; n < 4; n++) {
                const float s = acc[m][n][q];
                const int gcol = colBase + wc * 64 + n * 16 + lo;
                if (gcol != actual) {
                    unsigned long long p = ((unsigned long long)fkey(s) << 32) | (unsigned)(NB - 1 - gcol);
                    pk = (p > pk) ? p : pk;
                    if (fabsf(s - c0) < 0.15f) bm = min(bm, gcol);
                }
            }
            #pragma unroll
            for (int off = 1; off < 16; off <<= 1) {
                unsigned long long po = __shfl_xor(pk, off);
                int bo = __shfl_xor(bm, off);
                pk = (po > pk) ? po : pk;
                bm = min(bm, bo);
            }
            if (lo == 0) {
                bp2[blockIdx.y * 1024 + slotBase + rl] = (ushort_t)min(bm, 0xFFFF);
                fb2[blockIdx.y * 1024 + slotBase + rl] = pk;
            }
        }
    }
}

// ---------------- combine_p2: finalize missing rows ----------------
__global__ __launch_bounds__(256) void combine_p2_kernel(const ushort_t* __restrict__ bp2,
                                                         const unsigned long long* __restrict__ fb2,
                                                         const int* __restrict__ mrows,
                                                         const int* __restrict__ mcount,
                                                         int* __restrict__ neg) {
    int s = blockIdx.x * 256 + threadIdx.x;
    const int count = min(mcount[0], 1024);
    if (s >= count) return;
    int bmin = 0xFFFF;
    unsigned long long pk = 0ULL;
    for (int g = 0; g < 64; g++) {
        bmin = min(bmin, (int)bp2[g * 1024 + s]);
        unsigned long long f = fb2[g * 1024 + s];
        pk = (f > pk) ? f : pk;
    }
    neg[mrows[s]] = (bmin < 0xFFFF) ? bmin : (NB - 1 - (int)(unsigned)(pk & 0xFFFFFFFFull));
}

// ---------------- prep_head: cvt tcross/vcross (swizzled) only ----------------
__global__ __launch_bounds__(256) void prep_head_kernel(const float* __restrict__ tcross,
                                                        const float* __restrict__ vcross,
                                                        ushort_t* __restrict__ tb,
                                                        ushort_t* __restrict__ vb) {
    const int b = blockIdx.x;
    const float* in = (b < 1024) ? tcross : vcross;
    ushort_t* out = (b < 1024) ? tb : vb;
    int i = (b & 1023) * 256 + threadIdx.x;
    int row = i >> 5, cw = i & 31, kb = cw >> 3, c = cw & 7;
    int csrc = c ^ (row & 7);
    const float4* src = (const float4*)(in + (size_t)row * DD + kb * 64 + csrc * 8);
    ((uint4*)out)[i] = packbf8(src[0], src[1]);
}

// ==================== MFMA ITM head (proven R9 head2, verbatim) ====================
__device__ __forceinline__ void stage_head(const ushort_t* __restrict__ TCB,
                                           const ushort_t* __restrict__ VCB,
                                           const int* __restrict__ neg, int isNeg,
                                           const ushort_t* __restrict__ W1T,
                                           ushort_t* As, ushort_t* Bs,
                                           int rowBase, int kc, int tid) {
    #pragma unroll
    for (int i = 0; i < 2; ++i) {                 // A: 64 rows x 64 k
        int idx = i * 256 + tid;
        int r = idx >> 3, c8 = idx & 7;
        const ushort_t* src;
        if (kc < 256) {
            src = TCB + (size_t)(rowBase + r) * DD + kc + c8 * 8;
        } else {
            int rr = isNeg ? neg[rowBase + r] : (rowBase + r);
            int cs = c8 ^ ((r ^ rr) & 7);          // re-key rr&7 -> r&7
            src = VCB + (size_t)rr * DD + (kc - 256) + cs * 8;
        }
        __builtin_amdgcn_global_load_lds(
            (const __attribute__((address_space(1))) uint32_t*)src,
            (__attribute__((address_space(3))) uint32_t*)(As + idx * 8), 16, 0, 0);
    }
    #pragma unroll
    for (int i = 0; i < 8; ++i) {                 // B: 256 cols x 64 k (W1T pre-swizzled)
        int idx = i * 256 + tid;
        int n = idx >> 3, c8 = idx & 7;
        __builtin_amdgcn_global_load_lds(
            (const __attribute__((address_space(1))) uint32_t*)(W1T + (size_t)n * 512 + kc + c8 * 8),
            (__attribute__((address_space(3))) uint32_t*)(Bs + idx * 8), 16, 0, 0);
    }
}

__global__ __launch_bounds__(256) void head2_kernel(const ushort_t* __restrict__ TCB,
                                                    const ushort_t* __restrict__ VCB,
                                                    const ushort_t* __restrict__ W1T,
                                                    const int* __restrict__ neg,
                                                    const float* __restrict__ tcf,
                                                    const float* __restrict__ vcf,
                                                    const float* __restrict__ W1,
                                                    const float* __restrict__ b1,
                                                    const float* __restrict__ W2,
                                                    const float* __restrict__ b2,
                                                    float* __restrict__ acc_out) {
    __shared__ ushort_t As[2][64 * 64];
    __shared__ ushort_t Bs[2][256 * 64];
    __shared__ float dot_l[64];
    __shared__ float logit_l[64];

    const int tid = threadIdx.x;
    const int rowBase = blockIdx.x * 64;
    const int isNeg = blockIdx.y;
    const int lane = tid & 63;
    const int wcv = tid >> 6;
    const int lo = lane & 15, hi = lane >> 4;
    const int lx = lo & 7;

    // inline dot feature (fp32 exact): 4 threads per row
    {
        int r = tid >> 2, quarter = tid & 3;
        int grow = rowBase + r;
        int vrow = isNeg ? neg[grow] : grow;
        const float4* tp = (const float4*)(tcf + (size_t)grow * DD + quarter * 64);
        const float4* vp = (const float4*)(vcf + (size_t)vrow * DD + quarter * 64);
        float sd = 0.f;
        #pragma unroll
        for (int j = 0; j < 16; j++) {
            float4 a = tp[j], v = vp[j];
            sd += a.x * v.x + a.y * v.y + a.z * v.z + a.w * v.w;
        }
        sd += __shfl_xor(sd, 1);
        sd += __shfl_xor(sd, 2);
        if (quarter == 0) dot_l[r] = sd;
        if (tid < 64) logit_l[tid] = 0.f;
    }

    f32x4 acc[4][4];
    #pragma unroll
    for (int m = 0; m < 4; m++)
        #pragma unroll
        for (int n = 0; n < 4; n++) acc[m][n] = (f32x4){0.f, 0.f, 0.f, 0.f};

    stage_head(TCB, VCB, neg, isNeg, W1T, As[0], Bs[0], rowBase, 0, tid);
    __syncthreads();

    for (int kt = 0; kt < 8; ++kt) {
        const int buf = kt & 1;
        if (kt < 7)
            stage_head(TCB, VCB, neg, isNeg, W1T, As[buf ^ 1], Bs[buf ^ 1], rowBase, (kt + 1) * 64, tid);
        #pragma unroll
        for (int ksl = 0; ksl < 2; ksl++) {
            const int ch = ((((ksl << 2) | hi) ^ lx) << 3);
            bf16x8 a[4], b[4];
            #pragma unroll
            for (int m = 0; m < 4; m++)
                a[m] = *(const bf16x8*)&As[buf][(m * 16 + lo) * 64 + ch];
            #pragma unroll
            for (int n = 0; n < 4; n++)
                b[n] = *(const bf16x8*)&Bs[buf][(wcv * 64 + n * 16 + lo) * 64 + ch];
            #pragma unroll
            for (int m = 0; m < 4; m++)
                #pragma unroll
                for (int n = 0; n < 4; n++)
                    acc[m][n] = __builtin_amdgcn_mfma_f32_16x16x32_bf16(a[m], b[n], acc[m][n], 0, 0, 0);
        }
        __syncthreads();
    }

    float b1v[4], w5v[4], w2v[4];
    #pragma unroll
    for (int n = 0; n < 4; n++) {
        int cl = wcv * 64 + n * 16 + lo;
        b1v[n] = b1[cl];
        w5v[n] = W1[(size_t)512 * DD + cl];
        w2v[n] = W2[cl];
    }
    #pragma unroll
    for (int m = 0; m < 4; m++) {
        #pragma unroll
        for (int q = 0; q < 4; q++) {
            const int rl = m * 16 + hi * 4 + q;
            const float dt = dot_l[rl];
            float x = 0.f;
            #pragma unroll
            for (int n = 0; n < 4; n++) {
                float h = acc[m][n][q] + b1v[n] + dt * w5v[n];
                x += fmaxf(h, 0.f) * w2v[n];
            }
            #pragma unroll
            for (int off = 1; off < 16; off <<= 1) x += __shfl_xor(x, off);
            if (lo == 0) atomicAdd(&logit_l[rl], x);
        }
    }
    __syncthreads();

    if (tid < 64) {
        float x = logit_l[tid] + b2[0];
        float z = isNeg ? x : -x;                        // 1-sigmoid(x) = sigmoid(-x)
        float term = -logf(1.f / (1.f + expf(z)) + 1e-8f);
        #pragma unroll
        for (int off = 32; off; off >>= 1) term += __shfl_down(term, off);
        if (tid == 0) atomicAdd(acc_out, term);
    }
}

__global__ void finalize_kernel(const float* __restrict__ acc, float* __restrict__ out) {
    out[0] = acc[0] * (1.0f / (2.0f * (float)NB));
}

// ==================== launch ====================
extern "C" void kernel_launch(void* const* d_in, const int* in_sizes, int n_in,
                              void* d_out, int out_size, void* d_ws, size_t ws_size,
                              hipStream_t stream) {
    const float* vcross = (const float*)d_in[0];
    const float* tcross = (const float*)d_in[1];
    const float* vuni   = (const float*)d_in[2];
    const float* tuni   = (const float*)d_in[3];
    const float* W1     = (const float*)d_in[4];
    const float* b1     = (const float*)d_in[5];
    const float* W2     = (const float*)d_in[6];
    const float* b2     = (const float*)d_in[7];

    char* ws = (char*)d_ws;
    float* diag   = (float*)(ws + OFF_DIAG);
    int* neg      = (int*)(ws + OFF_NEG);
    int* mrows    = (int*)(ws + OFF_MROWS);
    float* acc    = (float*)(ws + OFF_ACC);
    int* mcount   = (int*)(ws + OFF_ACC + 4);
    ushort_t* bp1 = (ushort_t*)(ws + OFF_BP1);
    ushort_t* bp2 = (ushort_t*)(ws + OFF_BP2);
    unsigned long long* fb2 = (unsigned long long*)(ws + OFF_FB2);
    float* diag2  = (float*)(ws + OFF_DIAG2);
    ushort_t* A2  = (ushort_t*)(ws + OFF_A2);
    ushort_t* w1t = (ushort_t*)(ws + OFF_W1T);
    ushort_t* tb  = (ushort_t*)(ws + OFF_TB);
    ushort_t* vb  = (ushort_t*)(ws + OFF_VB);

    prep_uni_kernel<<<4128, 256, 0, stream>>>(tuni, vuni, W1, tb, vb, w1t, diag,
                                              (uint32_t*)(ws + OFF_ACC));
    mine_p1_kernel<<<dim3(64, 8), 256, 0, stream>>>(tb, vb, diag, bp1);
    combine_p1_kernel<<<NB / 256, 256, 0, stream>>>(bp1, neg, mrows, mcount);
    gather_p2_kernel<<<64, 256, 0, stream>>>(tb, diag, mrows, mcount, A2, diag2);
    mine_p2_kernel<<<dim3(8, 64), 256, 0, stream>>>(A2, vb, diag2, mrows, mcount, bp2, fb2);
    combine_p2_kernel<<<4, 256, 0, stream>>>(bp2, fb2, mrows, mcount, neg);
    prep_head_kernel<<<2048, 256, 0, stream>>>(tcross, vcross, tb, vb);
    head2_kernel<<<dim3(NB / 64, 2), 256, 0, stream>>>(tb, vb, w1t, neg, tcross, vcross,
                                                       W1, b1, W2, b2, acc);
    finalize_kernel<<<1, 1, 0, stream>>>(acc, (float*)d_out);
}